// Round 4
// baseline (306.516 us; speedup 1.0000x reference)
//
#include <hip/hip_runtime.h>
#include <stdint.h>

#define S_LEN 2048
#define NH 12
#define DM 768
#define DK 64
#define NB 2
#define MROWS (NB * S_LEN)  // 4096

typedef __attribute__((ext_vector_type(8))) short short8;
typedef __attribute__((ext_vector_type(4))) float f32x4;

__device__ __forceinline__ unsigned short bf16rne(float f) {
    union { float f; uint32_t u; } v; v.f = f;
    return (unsigned short)((v.u + 0x7FFFu + ((v.u >> 16) & 1u)) >> 16);
}

// ---------------- prep: fp32 -> bf16 for q,k,v ----------------
__global__ __launch_bounds__(256) void cvt_kernel(
        const float* __restrict__ q, const float* __restrict__ k, const float* __restrict__ v,
        unsigned short* __restrict__ qb, unsigned short* __restrict__ kb, unsigned short* __restrict__ vb) {
    const float* src = (blockIdx.y == 0) ? q : (blockIdx.y == 1) ? k : v;
    unsigned short* dst = (blockIdx.y == 0) ? qb : (blockIdx.y == 1) ? kb : vb;
    int i = (blockIdx.x * 256 + threadIdx.x) * 4;
    float4 x = *(const float4*)(src + i);
    uint32_t lo = (uint32_t)bf16rne(x.x) | ((uint32_t)bf16rne(x.y) << 16);
    uint32_t hi = (uint32_t)bf16rne(x.z) | ((uint32_t)bf16rne(x.w) << 16);
    uint2 o = make_uint2(lo, hi);
    *(uint2*)(dst + i) = o;
}

// ---------------- prep: weights -> bf16, B^T layout [N][K] ----------------
__global__ __launch_bounds__(256) void wtrans_kernel(
        const float* __restrict__ Wq, const float* __restrict__ Wk,
        const float* __restrict__ Wv, const float* __restrict__ Wo,
        unsigned short* __restrict__ WqT, unsigned short* __restrict__ WkT,
        unsigned short* __restrict__ WvT, unsigned short* __restrict__ WoT) {
    int which = blockIdx.y;
    const float* W = (which == 0) ? Wq : (which == 1) ? Wk : (which == 2) ? Wv : Wo;
    unsigned short* WT = (which == 0) ? WqT : (which == 1) ? WkT : (which == 2) ? WvT : WoT;
    int idx = blockIdx.x * 256 + threadIdx.x;  // 768*768
    int n = idx / DM, kd = idx % DM;
    float val;
    if (which < 3) { int h = n >> 6, kk = n & 63; val = W[(h * DM + kd) * DK + kk]; }
    else          { val = W[kd * DM + n]; }
    WT[idx] = bf16rne(val);
}

// ---------------- prep: pack mask into bits ----------------
__global__ __launch_bounds__(256) void mask_pack(const int* __restrict__ mask, uint32_t* __restrict__ pm) {
    int tid = blockIdx.x * 256 + threadIdx.x;  // 2*2048*2048 elems
    int m = mask[tid];
    unsigned long long bm = __ballot(m != 0);
    if ((threadIdx.x & 63) == 0) {
        *(unsigned long long*)(pm + (tid >> 5)) = bm;
    }
}

// ---------------- GEMM core: C[128x128] += A[128xK] * BT[128xK]^T ----------------
__device__ __forceinline__ void gemm_core(const unsigned short* __restrict__ A,
                                          const unsigned short* __restrict__ BT,
                                          unsigned short* As, unsigned short* Bs,
                                          f32x4 (&acc)[4][4]) {
    const int tid = threadIdx.x;
    const int lane = tid & 63, wid = tid >> 6;
    const int ww = wid & 1, wh = wid >> 1;
    const int quad = lane >> 4, l16 = lane & 15;
    const int srow = tid >> 2, scol = (tid & 3) << 3;
    const unsigned short* Ag = A + srow * DM + scol;
    const unsigned short* Bg = BT + srow * DM + scol;
    for (int kt = 0; kt < DM; kt += 32) {
        __syncthreads();
        short8 a0 = *(const short8*)(Ag + kt);
        short8 a1 = *(const short8*)(Ag + 64 * DM + kt);
        short8 b0 = *(const short8*)(Bg + kt);
        short8 b1 = *(const short8*)(Bg + 64 * DM + kt);
        *(short8*)&As[srow * 40 + scol] = a0;
        *(short8*)&As[(srow + 64) * 40 + scol] = a1;
        *(short8*)&Bs[srow * 40 + scol] = b0;
        *(short8*)&Bs[(srow + 64) * 40 + scol] = b1;
        __syncthreads();
        short8 af[4], bf[4];
#pragma unroll
        for (int i = 0; i < 4; ++i) af[i] = *(const short8*)&As[(wh * 64 + i * 16 + l16) * 40 + quad * 8];
#pragma unroll
        for (int j = 0; j < 4; ++j) bf[j] = *(const short8*)&Bs[(ww * 64 + j * 16 + l16) * 40 + quad * 8];
#pragma unroll
        for (int i = 0; i < 4; ++i)
#pragma unroll
            for (int j = 0; j < 4; ++j)
                acc[i][j] = __builtin_amdgcn_mfma_f32_16x16x32_bf16(af[i], bf[j], acc[i][j], 0, 0, 0);
    }
}

// ---------------- projections: q,k -> [M, H*64] bf16 ; v -> vhT[b,h,d,s] bf16 ----------------
__global__ __launch_bounds__(256) void proj_gemm(
        const unsigned short* __restrict__ qb, const unsigned short* __restrict__ kb,
        const unsigned short* __restrict__ vb,
        const unsigned short* __restrict__ WqT, const unsigned short* __restrict__ WkT,
        const unsigned short* __restrict__ WvT,
        unsigned short* __restrict__ qh, unsigned short* __restrict__ kh,
        unsigned short* __restrict__ vhT) {
    __shared__ __align__(16) unsigned short As[128 * 40];
    __shared__ __align__(16) unsigned short Bs[128 * 40];
    const int z = blockIdx.z;
    const unsigned short* A = (z == 0) ? qb : (z == 1) ? kb : vb;
    const unsigned short* BT = (z == 0) ? WqT : (z == 1) ? WkT : WvT;
    f32x4 acc[4][4] = {};
    gemm_core(A + (size_t)blockIdx.x * 128 * DM, BT + (size_t)blockIdx.y * 128 * DM, As, Bs, acc);

    const int tid = threadIdx.x;
    const int lane = tid & 63, wid = tid >> 6;
    const int ww = wid & 1, wh = wid >> 1;
    const int quad = lane >> 4, l16 = lane & 15;
    const int row0 = blockIdx.x * 128 + wh * 64;
    const int col0 = blockIdx.y * 128 + ww * 64;
    if (z < 2) {
        unsigned short* C = z ? kh : qh;
#pragma unroll
        for (int i = 0; i < 4; ++i)
#pragma unroll
            for (int j = 0; j < 4; ++j)
#pragma unroll
                for (int r = 0; r < 4; ++r)
                    C[(size_t)(row0 + i * 16 + quad * 4 + r) * DM + col0 + j * 16 + l16] = bf16rne(acc[i][j][r]);
    } else {
#pragma unroll
        for (int i = 0; i < 4; ++i)
#pragma unroll
            for (int j = 0; j < 4; ++j) {
                int row = row0 + i * 16 + quad * 4;  // = b*2048 + s, 4 consecutive s
                int col = col0 + j * 16 + l16;       // = h*64 + d
                int bb = row >> 11, s = row & 2047;
                int hh = col >> 6, d = col & 63;
                uint32_t lo = (uint32_t)bf16rne(acc[i][j][0]) | ((uint32_t)bf16rne(acc[i][j][1]) << 16);
                uint32_t hi = (uint32_t)bf16rne(acc[i][j][2]) | ((uint32_t)bf16rne(acc[i][j][3]) << 16);
                uint2 o = make_uint2(lo, hi);
                *(uint2*)&vhT[(size_t)((bb * NH + hh) * DK + d) * S_LEN + s] = o;
            }
    }
}

// ---------------- flash attention: 2 waves/block, 32 q-rows/wave ----------------
__global__ __launch_bounds__(128) void attn_kernel(
        const unsigned short* __restrict__ qh, const unsigned short* __restrict__ kh,
        const unsigned short* __restrict__ vhT, const uint32_t* __restrict__ pm,
        unsigned short* __restrict__ ao) {
    const int qt = blockIdx.x, h = blockIdx.y, b = blockIdx.z;
    const int tid = threadIdx.x, w = tid >> 6, lane = tid & 63;
    const int quad = lane >> 4, l16 = lane & 15;
    __shared__ __align__(16) unsigned short Ks[64 * 72];   // [key][d]
    __shared__ __align__(16) unsigned short Vs[64 * 72];   // [d][key]
    __shared__ __align__(16) unsigned short Ps[2][32 * 72];  // per-wave P round-trip

    // Q A-frags: two 16-row blocks per wave (rows qrow0 + mi*16 + l16)
    const int qrow0 = qt * 64 + w * 32;
    short8 qf[2][2];
#pragma unroll
    for (int mi = 0; mi < 2; ++mi) {
        const size_t qbase = (size_t)(b * S_LEN + qrow0 + mi * 16 + l16) * DM + h * DK;
        qf[mi][0] = *(const short8*)&qh[qbase + quad * 8];
        qf[mi][1] = *(const short8*)&qh[qbase + 32 + quad * 8];
    }
    // ones B-frag (only row n=0 is 1.0): lsum = P x ones via MFMA, lands in col 0
    short8 of = {};
    if (l16 == 0) {
#pragma unroll
        for (int j = 0; j < 8; ++j) of[j] = (short)0x3F80;
    }

    f32x4 out[2][4] = {};
    f32x4 outl[2] = {};

    // staging: 128 threads x 64B each per tile (K and V)
    const int srow = tid >> 1, sh = (tid & 1) * 32;
    const unsigned short* Kg = kh + (size_t)b * S_LEN * DM + h * DK;
    const unsigned short* Vg = vhT + (size_t)((b * NH + h) * DK) * S_LEN;
    const uint32_t* pmb = pm + (size_t)(b * S_LEN + qrow0 + quad * 4) * 64;
    const float SCL = 0.18033688011112042f;  // 0.125 * log2(e)
    const float FM = 12.0f;  // fixed exponent offset (softmax scale-invariant)

    for (int kt = 0; kt < S_LEN; kt += 64) {
        __syncthreads();
#pragma unroll
        for (int j = 0; j < 4; ++j) {
            *(short8*)&Ks[srow * 72 + sh + j * 8] = *(const short8*)&Kg[(size_t)(kt + srow) * DM + sh + j * 8];
            *(short8*)&Vs[srow * 72 + sh + j * 8] = *(const short8*)&Vg[(size_t)srow * S_LEN + kt + sh + j * 8];
        }
        __syncthreads();

        uint2 mw[2][4];
#pragma unroll
        for (int mi = 0; mi < 2; ++mi)
#pragma unroll
            for (int r = 0; r < 4; ++r)
                mw[mi][r] = *(const uint2*)&pmb[(size_t)(mi * 16 + r) * 64 + (kt >> 5)];

#pragma unroll
        for (int cb = 0; cb < 4; ++cb) {
            short8 kf0 = *(const short8*)&Ks[(cb * 16 + l16) * 72 + quad * 8];
            short8 kf1 = *(const short8*)&Ks[(cb * 16 + l16) * 72 + 32 + quad * 8];
            const int boff = ((cb & 1) << 4) + l16;
#pragma unroll
            for (int mi = 0; mi < 2; ++mi) {
                f32x4 zz = {0.f, 0.f, 0.f, 0.f};
                zz = __builtin_amdgcn_mfma_f32_16x16x32_bf16(qf[mi][0], kf0, zz, 0, 0, 0);
                zz = __builtin_amdgcn_mfma_f32_16x16x32_bf16(qf[mi][1], kf1, zz, 0, 0, 0);
#pragma unroll
                for (int r = 0; r < 4; ++r) {
                    float e = __builtin_amdgcn_exp2f(fmaf(zz[r], SCL, -FM));
                    uint32_t mword = (cb >> 1) ? mw[mi][r].y : mw[mi][r].x;
                    int32_t mneg = __builtin_amdgcn_sbfe((int32_t)mword, boff, 1);  // 0 or -1
                    uint32_t up = (__float_as_uint(e) & (uint32_t)mneg) + 0x8000u;  // mask, round-half-up
                    Ps[w][(mi * 16 + quad * 4 + r) * 72 + cb * 16 + l16] = (unsigned short)(up >> 16);
                }
            }
        }

        short8 pf0[2], pf1[2];
#pragma unroll
        for (int mi = 0; mi < 2; ++mi) {
            pf0[mi] = *(const short8*)&Ps[w][(mi * 16 + l16) * 72 + quad * 8];
            pf1[mi] = *(const short8*)&Ps[w][(mi * 16 + l16) * 72 + 32 + quad * 8];
        }
#pragma unroll
        for (int cb2 = 0; cb2 < 4; ++cb2) {
            short8 vf0 = *(const short8*)&Vs[(cb2 * 16 + l16) * 72 + quad * 8];
            short8 vf1 = *(const short8*)&Vs[(cb2 * 16 + l16) * 72 + 32 + quad * 8];
#pragma unroll
            for (int mi = 0; mi < 2; ++mi) {
                out[mi][cb2] = __builtin_amdgcn_mfma_f32_16x16x32_bf16(pf0[mi], vf0, out[mi][cb2], 0, 0, 0);
                out[mi][cb2] = __builtin_amdgcn_mfma_f32_16x16x32_bf16(pf1[mi], vf1, out[mi][cb2], 0, 0, 0);
            }
        }
#pragma unroll
        for (int mi = 0; mi < 2; ++mi) {
            outl[mi] = __builtin_amdgcn_mfma_f32_16x16x32_bf16(pf0[mi], of, outl[mi], 0, 0, 0);
            outl[mi] = __builtin_amdgcn_mfma_f32_16x16x32_bf16(pf1[mi], of, outl[mi], 0, 0, 0);
        }
    }

#pragma unroll
    for (int mi = 0; mi < 2; ++mi) {
        float rls[4];
#pragma unroll
        for (int r = 0; r < 4; ++r) {
            float l = outl[mi][r];  // col 0 holds lsum, cols 1..15 are 0
#pragma unroll
            for (int d = 1; d < 16; d <<= 1) l += __shfl_xor(l, d);
            rls[r] = 1.f / fmaxf(l, 1e-37f);
        }
#pragma unroll
        for (int cb2 = 0; cb2 < 4; ++cb2)
#pragma unroll
            for (int r = 0; r < 4; ++r) {
                float val = out[mi][cb2][r] * rls[r];
                ao[(size_t)(b * S_LEN + qrow0 + mi * 16 + quad * 4 + r) * DM + h * DK + cb2 * 16 + l16] = bf16rne(val);
            }
    }
}

// ---------------- output projection: fp32 store ----------------
__global__ __launch_bounds__(256) void out_gemm(const unsigned short* __restrict__ ao,
                                                const unsigned short* __restrict__ WoT,
                                                float* __restrict__ C) {
    __shared__ __align__(16) unsigned short As[128 * 40];
    __shared__ __align__(16) unsigned short Bs[128 * 40];
    f32x4 acc[4][4] = {};
    gemm_core(ao + (size_t)blockIdx.x * 128 * DM, WoT + (size_t)blockIdx.y * 128 * DM, As, Bs, acc);
    const int tid = threadIdx.x;
    const int lane = tid & 63, wid = tid >> 6;
    const int ww = wid & 1, wh = wid >> 1;
    const int quad = lane >> 4, l16 = lane & 15;
    const int row0 = blockIdx.x * 128 + wh * 64;
    const int col0 = blockIdx.y * 128 + ww * 64;
#pragma unroll
    for (int i = 0; i < 4; ++i)
#pragma unroll
        for (int j = 0; j < 4; ++j)
#pragma unroll
            for (int r = 0; r < 4; ++r)
                C[(size_t)(row0 + i * 16 + quad * 4 + r) * DM + col0 + j * 16 + l16] = acc[i][j][r];
}

extern "C" void kernel_launch(void* const* d_in, const int* in_sizes, int n_in,
                              void* d_out, int out_size, void* d_ws, size_t ws_size,
                              hipStream_t stream) {
    const float* q = (const float*)d_in[0];
    const float* k = (const float*)d_in[1];
    const float* v = (const float*)d_in[2];
    const int* mask = (const int*)d_in[3];
    const float* Wq = (const float*)d_in[4];
    const float* Wk = (const float*)d_in[5];
    const float* Wv = (const float*)d_in[6];
    const float* Wo = (const float*)d_in[7];
    float* out = (float*)d_out;

    char* ws = (char*)d_ws;
    size_t off = 0;
    auto alloc = [&](size_t bytes) {
        void* p = ws + off;
        off += (bytes + 255) & ~(size_t)255;
        return p;
    };
    const size_t MAT = (size_t)MROWS * DM * 2;      // 6291456 B
    const size_t WMAT = (size_t)DM * DM * 2;        // 1179648 B
    unsigned short* qb  = (unsigned short*)alloc(MAT);
    unsigned short* kb  = (unsigned short*)alloc(MAT);
    unsigned short* vb  = (unsigned short*)alloc(MAT);
    unsigned short* WqT = (unsigned short*)alloc(WMAT);
    unsigned short* WkT = (unsigned short*)alloc(WMAT);
    unsigned short* WvT = (unsigned short*)alloc(WMAT);
    unsigned short* WoT = (unsigned short*)alloc(WMAT);
    unsigned short* qh  = (unsigned short*)alloc(MAT);
    unsigned short* kh  = (unsigned short*)alloc(MAT);
    unsigned short* vhT = (unsigned short*)alloc(MAT);
    unsigned short* ao  = (unsigned short*)alloc(MAT);
    uint32_t* pmask     = (uint32_t*)alloc((size_t)NB * S_LEN * 64 * 4);

    cvt_kernel<<<dim3(3072, 3), 256, 0, stream>>>(q, k, v, qb, kb, vb);
    wtrans_kernel<<<dim3(2304, 4), 256, 0, stream>>>(Wq, Wk, Wv, Wo, WqT, WkT, WvT, WoT);
    mask_pack<<<dim3(32768), 256, 0, stream>>>(mask, pmask);
    proj_gemm<<<dim3(32, 6, 3), 256, 0, stream>>>(qb, kb, vb, WqT, WkT, WvT, qh, kh, vhT);
    attn_kernel<<<dim3(32, 12, 2), 128, 0, stream>>>(qh, kh, vhT, pmask, ao);
    out_gemm<<<dim3(32, 6), 256, 0, stream>>>(ao, WoT, out);
}

// Round 5
// 242.094 us; speedup vs baseline: 1.2661x; 1.2661x over previous
//
#include <hip/hip_runtime.h>
#include <stdint.h>

#define S_LEN 2048
#define NH 12
#define DM 768
#define DK 64
#define NB 2
#define MROWS (NB * S_LEN)  // 4096

typedef __attribute__((ext_vector_type(8))) short short8;
typedef __attribute__((ext_vector_type(4))) float f32x4;

__device__ __forceinline__ unsigned short bf16rne(float f) {
    union { float f; uint32_t u; } v; v.f = f;
    return (unsigned short)((v.u + 0x7FFFu + ((v.u >> 16) & 1u)) >> 16);
}

// ---------------- prep: fp32 -> bf16 for q,k,v ----------------
__global__ __launch_bounds__(256) void cvt_kernel(
        const float* __restrict__ q, const float* __restrict__ k, const float* __restrict__ v,
        unsigned short* __restrict__ qb, unsigned short* __restrict__ kb, unsigned short* __restrict__ vb) {
    const float* src = (blockIdx.y == 0) ? q : (blockIdx.y == 1) ? k : v;
    unsigned short* dst = (blockIdx.y == 0) ? qb : (blockIdx.y == 1) ? kb : vb;
    int i = (blockIdx.x * 256 + threadIdx.x) * 4;
    float4 x = *(const float4*)(src + i);
    uint32_t lo = (uint32_t)bf16rne(x.x) | ((uint32_t)bf16rne(x.y) << 16);
    uint32_t hi = (uint32_t)bf16rne(x.z) | ((uint32_t)bf16rne(x.w) << 16);
    uint2 o = make_uint2(lo, hi);
    *(uint2*)(dst + i) = o;
}

// ---------------- prep: weights -> bf16, B^T layout [N][K] ----------------
__global__ __launch_bounds__(256) void wtrans_kernel(
        const float* __restrict__ Wq, const float* __restrict__ Wk,
        const float* __restrict__ Wv, const float* __restrict__ Wo,
        unsigned short* __restrict__ WqT, unsigned short* __restrict__ WkT,
        unsigned short* __restrict__ WvT, unsigned short* __restrict__ WoT) {
    int which = blockIdx.y;
    const float* W = (which == 0) ? Wq : (which == 1) ? Wk : (which == 2) ? Wv : Wo;
    unsigned short* WT = (which == 0) ? WqT : (which == 1) ? WkT : (which == 2) ? WvT : WoT;
    int idx = blockIdx.x * 256 + threadIdx.x;  // 768*768
    int n = idx / DM, kd = idx % DM;
    float val;
    if (which < 3) { int h = n >> 6, kk = n & 63; val = W[(h * DM + kd) * DK + kk]; }
    else          { val = W[kd * DM + n]; }
    WT[idx] = bf16rne(val);
}

// ---------------- prep: pack mask into bits ----------------
__global__ __launch_bounds__(256) void mask_pack(const int* __restrict__ mask, uint32_t* __restrict__ pm) {
    int tid = blockIdx.x * 256 + threadIdx.x;  // 2*2048*2048 elems
    int m = mask[tid];
    unsigned long long bm = __ballot(m != 0);
    if ((threadIdx.x & 63) == 0) {
        *(unsigned long long*)(pm + (tid >> 5)) = bm;
    }
}

// ---------------- GEMM core (m97-style): global_load_lds width-16 staging ----------------
// LDS tiles 128x32 unpadded (stride 64B): b128 frag reads are 2-way aliased = free (m136);
// no padding allowed — global_load_lds lands at wave-uniform base + lane*16 (m104/m108).
__device__ __forceinline__ void gemm_core(const unsigned short* __restrict__ A,
                                          const unsigned short* __restrict__ BT,
                                          unsigned short* As, unsigned short* Bs,
                                          f32x4 (&acc)[4][4]) {
    const int tid = threadIdx.x;
    const int lane = tid & 63, wid = tid >> 6;
    const int ww = wid & 1, wh = wid >> 1;
    const int quad = lane >> 4, l16 = lane & 15;
    const int lr = lane >> 2;        // row within 16-row chunk
    const int lc = (lane & 3) * 8;   // col offset in shorts
    typedef __attribute__((address_space(1))) const unsigned int* gp1;
    typedef __attribute__((address_space(3))) unsigned int* lp3;
    const unsigned short* Ag = A + (size_t)(wid * 32 + lr) * DM + lc;
    const unsigned short* Bg = BT + (size_t)(wid * 32 + lr) * DM + lc;
    unsigned short* Al = &As[wid * 32 * 32];
    unsigned short* Bl = &Bs[wid * 32 * 32];
    for (int kt = 0; kt < DM; kt += 32) {
        __syncthreads();
        __builtin_amdgcn_global_load_lds((gp1)(const void*)(Ag + kt),            (lp3)(void*)Al,             16, 0, 0);
        __builtin_amdgcn_global_load_lds((gp1)(const void*)(Ag + 16 * DM + kt),  (lp3)(void*)(Al + 16 * 32), 16, 0, 0);
        __builtin_amdgcn_global_load_lds((gp1)(const void*)(Bg + kt),            (lp3)(void*)Bl,             16, 0, 0);
        __builtin_amdgcn_global_load_lds((gp1)(const void*)(Bg + 16 * DM + kt),  (lp3)(void*)(Bl + 16 * 32), 16, 0, 0);
        __syncthreads();
        short8 af[4], bf[4];
#pragma unroll
        for (int i = 0; i < 4; ++i) af[i] = *(const short8*)&As[(wh * 64 + i * 16 + l16) * 32 + quad * 8];
#pragma unroll
        for (int j = 0; j < 4; ++j) bf[j] = *(const short8*)&Bs[(ww * 64 + j * 16 + l16) * 32 + quad * 8];
#pragma unroll
        for (int i = 0; i < 4; ++i)
#pragma unroll
            for (int j = 0; j < 4; ++j)
                acc[i][j] = __builtin_amdgcn_mfma_f32_16x16x32_bf16(af[i], bf[j], acc[i][j], 0, 0, 0);
    }
}

// ---------------- projections: q,k -> [M, H*64] bf16 ; v -> vhT[b,h,d,s] bf16 ----------------
__global__ __launch_bounds__(256) void proj_gemm(
        const unsigned short* __restrict__ qb, const unsigned short* __restrict__ kb,
        const unsigned short* __restrict__ vb,
        const unsigned short* __restrict__ WqT, const unsigned short* __restrict__ WkT,
        const unsigned short* __restrict__ WvT,
        unsigned short* __restrict__ qh, unsigned short* __restrict__ kh,
        unsigned short* __restrict__ vhT) {
    __shared__ __align__(16) unsigned short As[128 * 32];
    __shared__ __align__(16) unsigned short Bs[128 * 32];
    const int z = blockIdx.z;
    const unsigned short* A = (z == 0) ? qb : (z == 1) ? kb : vb;
    const unsigned short* BT = (z == 0) ? WqT : (z == 1) ? WkT : WvT;
    f32x4 acc[4][4] = {};
    gemm_core(A + (size_t)blockIdx.x * 128 * DM, BT + (size_t)blockIdx.y * 128 * DM, As, Bs, acc);

    const int tid = threadIdx.x;
    const int lane = tid & 63, wid = tid >> 6;
    const int ww = wid & 1, wh = wid >> 1;
    const int quad = lane >> 4, l16 = lane & 15;
    const int row0 = blockIdx.x * 128 + wh * 64;
    const int col0 = blockIdx.y * 128 + ww * 64;
    if (z < 2) {
        unsigned short* C = z ? kh : qh;
#pragma unroll
        for (int i = 0; i < 4; ++i)
#pragma unroll
            for (int j = 0; j < 4; ++j)
#pragma unroll
                for (int r = 0; r < 4; ++r)
                    C[(size_t)(row0 + i * 16 + quad * 4 + r) * DM + col0 + j * 16 + l16] = bf16rne(acc[i][j][r]);
    } else {
#pragma unroll
        for (int i = 0; i < 4; ++i)
#pragma unroll
            for (int j = 0; j < 4; ++j) {
                int row = row0 + i * 16 + quad * 4;  // = b*2048 + s, 4 consecutive s
                int col = col0 + j * 16 + l16;       // = h*64 + d
                int bb = row >> 11, s = row & 2047;
                int hh = col >> 6, d = col & 63;
                uint32_t lo = (uint32_t)bf16rne(acc[i][j][0]) | ((uint32_t)bf16rne(acc[i][j][1]) << 16);
                uint32_t hi = (uint32_t)bf16rne(acc[i][j][2]) | ((uint32_t)bf16rne(acc[i][j][3]) << 16);
                uint2 o = make_uint2(lo, hi);
                *(uint2*)&vhT[(size_t)((bb * NH + hh) * DK + d) * S_LEN + s] = o;
            }
    }
}

// ---------------- flash attention: 4 waves/block, 32 q-rows/wave, K-split 2 ----------------
// Writes UNnormalized bf16 partial out + fp32 lsum (fixed-exponent softmax is additive over key chunks).
__global__ __launch_bounds__(256) void attn_kernel(
        const unsigned short* __restrict__ qh, const unsigned short* __restrict__ kh,
        const unsigned short* __restrict__ vhT, const uint32_t* __restrict__ pm,
        unsigned short* __restrict__ pob, float* __restrict__ lsb) {
    const int qt = blockIdx.x, h = blockIdx.y;
    const int b = blockIdx.z >> 1, ks = blockIdx.z & 1;
    const int tid = threadIdx.x, w = tid >> 6, lane = tid & 63;
    const int quad = lane >> 4, l16 = lane & 15;
    __shared__ __align__(16) unsigned short Ks[64 * 72];     // [key][d]
    __shared__ __align__(16) unsigned short Vs[64 * 72];     // [d][key]
    __shared__ __align__(16) unsigned short Ps[4][32 * 72];  // per-wave P round-trip

    // Q A-frags: two 16-row blocks per wave
    const int qrow0 = qt * 128 + w * 32;
    short8 qf[2][2];
#pragma unroll
    for (int mi = 0; mi < 2; ++mi) {
        const size_t qbase = (size_t)(b * S_LEN + qrow0 + mi * 16 + l16) * DM + h * DK;
        qf[mi][0] = *(const short8*)&qh[qbase + quad * 8];
        qf[mi][1] = *(const short8*)&qh[qbase + 32 + quad * 8];
    }
    // ones B-frag (only row n=0 is 1.0): lsum = P x ones via MFMA, lands in col 0
    short8 of = {};
    if (l16 == 0) {
#pragma unroll
        for (int j = 0; j < 8; ++j) of[j] = (short)0x3F80;
    }

    f32x4 out[2][4] = {};
    f32x4 outl[2] = {};

    // staging: 256 threads, 64 rows x 64 cols, 16 shorts/thread
    const int srow = tid >> 2, scol = (tid & 3) << 4;
    const unsigned short* Kg = kh + (size_t)b * S_LEN * DM + h * DK;
    const unsigned short* Vg = vhT + (size_t)((b * NH + h) * DK) * S_LEN;
    const uint32_t* pmb = pm + (size_t)(b * S_LEN + qrow0 + quad * 4) * 64;
    const float SCL = 0.18033688011112042f;  // 0.125 * log2(e)
    const float FM = 12.0f;  // fixed exponent offset (softmax scale-invariant)
    const int kt0 = ks * (S_LEN / 2);

    for (int kt = kt0; kt < kt0 + S_LEN / 2; kt += 64) {
        __syncthreads();
        *(short8*)&Ks[srow * 72 + scol]     = *(const short8*)&Kg[(size_t)(kt + srow) * DM + scol];
        *(short8*)&Ks[srow * 72 + scol + 8] = *(const short8*)&Kg[(size_t)(kt + srow) * DM + scol + 8];
        *(short8*)&Vs[srow * 72 + scol]     = *(const short8*)&Vg[(size_t)srow * S_LEN + kt + scol];
        *(short8*)&Vs[srow * 72 + scol + 8] = *(const short8*)&Vg[(size_t)srow * S_LEN + kt + scol + 8];
        __syncthreads();

        uint2 mw[2][4];
#pragma unroll
        for (int mi = 0; mi < 2; ++mi)
#pragma unroll
            for (int r = 0; r < 4; ++r)
                mw[mi][r] = *(const uint2*)&pmb[(size_t)(mi * 16 + r) * 64 + (kt >> 5)];

#pragma unroll
        for (int cb = 0; cb < 4; ++cb) {
            short8 kf0 = *(const short8*)&Ks[(cb * 16 + l16) * 72 + quad * 8];
            short8 kf1 = *(const short8*)&Ks[(cb * 16 + l16) * 72 + 32 + quad * 8];
            const int boff = ((cb & 1) << 4) + l16;
#pragma unroll
            for (int mi = 0; mi < 2; ++mi) {
                f32x4 zz = {0.f, 0.f, 0.f, 0.f};
                zz = __builtin_amdgcn_mfma_f32_16x16x32_bf16(qf[mi][0], kf0, zz, 0, 0, 0);
                zz = __builtin_amdgcn_mfma_f32_16x16x32_bf16(qf[mi][1], kf1, zz, 0, 0, 0);
#pragma unroll
                for (int r = 0; r < 4; ++r) {
                    float e = __builtin_amdgcn_exp2f(fmaf(zz[r], SCL, -FM));
                    uint32_t mword = (cb >> 1) ? mw[mi][r].y : mw[mi][r].x;
                    int32_t mneg = __builtin_amdgcn_sbfe((int32_t)mword, boff, 1);  // 0 or -1
                    uint32_t up = (__float_as_uint(e) & (uint32_t)mneg) + 0x8000u;  // mask, round-half-up
                    Ps[w][(mi * 16 + quad * 4 + r) * 72 + cb * 16 + l16] = (unsigned short)(up >> 16);
                }
            }
        }

        short8 pf0[2], pf1[2];
#pragma unroll
        for (int mi = 0; mi < 2; ++mi) {
            pf0[mi] = *(const short8*)&Ps[w][(mi * 16 + l16) * 72 + quad * 8];
            pf1[mi] = *(const short8*)&Ps[w][(mi * 16 + l16) * 72 + 32 + quad * 8];
        }
#pragma unroll
        for (int cb2 = 0; cb2 < 4; ++cb2) {
            short8 vf0 = *(const short8*)&Vs[(cb2 * 16 + l16) * 72 + quad * 8];
            short8 vf1 = *(const short8*)&Vs[(cb2 * 16 + l16) * 72 + 32 + quad * 8];
#pragma unroll
            for (int mi = 0; mi < 2; ++mi) {
                out[mi][cb2] = __builtin_amdgcn_mfma_f32_16x16x32_bf16(pf0[mi], vf0, out[mi][cb2], 0, 0, 0);
                out[mi][cb2] = __builtin_amdgcn_mfma_f32_16x16x32_bf16(pf1[mi], vf1, out[mi][cb2], 0, 0, 0);
            }
        }
#pragma unroll
        for (int mi = 0; mi < 2; ++mi) {
            outl[mi] = __builtin_amdgcn_mfma_f32_16x16x32_bf16(pf0[mi], of, outl[mi], 0, 0, 0);
            outl[mi] = __builtin_amdgcn_mfma_f32_16x16x32_bf16(pf1[mi], of, outl[mi], 0, 0, 0);
        }
    }

    const int pz = b * 2 + ks;
#pragma unroll
    for (int mi = 0; mi < 2; ++mi) {
#pragma unroll
        for (int r = 0; r < 4; ++r) {
            float l = outl[mi][r];  // col 0 holds lsum, others 0
#pragma unroll
            for (int d = 1; d < 16; d <<= 1) l += __shfl_xor(l, d);
            const int row = qrow0 + mi * 16 + quad * 4 + r;
            if (l16 == 0)
                lsb[((size_t)pz * NH + h) * S_LEN + row] = l;
#pragma unroll
            for (int cb2 = 0; cb2 < 4; ++cb2)
                pob[((size_t)pz * S_LEN + row) * DM + h * DK + cb2 * 16 + l16] = bf16rne(out[mi][cb2][r]);
        }
    }
}

// ---------------- merge the two K-chunk partials -> ao bf16 ----------------
__global__ __launch_bounds__(256) void merge_kernel(const unsigned short* __restrict__ pob,
                                                    const float* __restrict__ lsb,
                                                    unsigned short* __restrict__ ao) {
    int t = blockIdx.x * 256 + threadIdx.x;   // 4096*192 threads, 4 elems each
    int sg = t / 192;                          // b*S + s
    int c = (t - sg * 192) * 4;                // col in [0,768)
    int b = sg >> 11, s = sg & 2047, h = c >> 6;
    float l = lsb[((size_t)(b * 2) * NH + h) * S_LEN + s] +
              lsb[((size_t)(b * 2 + 1) * NH + h) * S_LEN + s];
    float rl = 1.f / fmaxf(l, 1e-37f);
    uint2 a0 = *(const uint2*)&pob[((size_t)(b * 2) * S_LEN + s) * DM + c];
    uint2 a1 = *(const uint2*)&pob[((size_t)(b * 2 + 1) * S_LEN + s) * DM + c];
    float f0 = __uint_as_float((a0.x & 0xFFFFu) << 16) + __uint_as_float((a1.x & 0xFFFFu) << 16);
    float f1 = __uint_as_float((a0.x >> 16) << 16)     + __uint_as_float((a1.x >> 16) << 16);
    float f2 = __uint_as_float((a0.y & 0xFFFFu) << 16) + __uint_as_float((a1.y & 0xFFFFu) << 16);
    float f3 = __uint_as_float((a0.y >> 16) << 16)     + __uint_as_float((a1.y >> 16) << 16);
    uint32_t lo = (uint32_t)bf16rne(f0 * rl) | ((uint32_t)bf16rne(f1 * rl) << 16);
    uint32_t hi = (uint32_t)bf16rne(f2 * rl) | ((uint32_t)bf16rne(f3 * rl) << 16);
    uint2 o = make_uint2(lo, hi);
    *(uint2*)&ao[(size_t)sg * DM + c] = o;
}

// ---------------- output projection: fp32 store ----------------
__global__ __launch_bounds__(256) void out_gemm(const unsigned short* __restrict__ ao,
                                                const unsigned short* __restrict__ WoT,
                                                float* __restrict__ C) {
    __shared__ __align__(16) unsigned short As[128 * 32];
    __shared__ __align__(16) unsigned short Bs[128 * 32];
    f32x4 acc[4][4] = {};
    gemm_core(ao + (size_t)blockIdx.x * 128 * DM, WoT + (size_t)blockIdx.y * 128 * DM, As, Bs, acc);
    const int tid = threadIdx.x;
    const int lane = tid & 63, wid = tid >> 6;
    const int ww = wid & 1, wh = wid >> 1;
    const int quad = lane >> 4, l16 = lane & 15;
    const int row0 = blockIdx.x * 128 + wh * 64;
    const int col0 = blockIdx.y * 128 + ww * 64;
#pragma unroll
    for (int i = 0; i < 4; ++i)
#pragma unroll
        for (int j = 0; j < 4; ++j)
#pragma unroll
            for (int r = 0; r < 4; ++r)
                C[(size_t)(row0 + i * 16 + quad * 4 + r) * DM + col0 + j * 16 + l16] = acc[i][j][r];
}

extern "C" void kernel_launch(void* const* d_in, const int* in_sizes, int n_in,
                              void* d_out, int out_size, void* d_ws, size_t ws_size,
                              hipStream_t stream) {
    const float* q = (const float*)d_in[0];
    const float* k = (const float*)d_in[1];
    const float* v = (const float*)d_in[2];
    const int* mask = (const int*)d_in[3];
    const float* Wq = (const float*)d_in[4];
    const float* Wk = (const float*)d_in[5];
    const float* Wv = (const float*)d_in[6];
    const float* Wo = (const float*)d_in[7];
    float* out = (float*)d_out;

    char* ws = (char*)d_ws;
    size_t off = 0;
    auto alloc = [&](size_t bytes) {
        void* p = ws + off;
        off += (bytes + 255) & ~(size_t)255;
        return p;
    };
    const size_t MAT = (size_t)MROWS * DM * 2;      // 6291456 B
    const size_t WMAT = (size_t)DM * DM * 2;        // 1179648 B
    unsigned short* qb  = (unsigned short*)alloc(MAT);
    unsigned short* kb  = (unsigned short*)alloc(MAT);
    unsigned short* vb  = (unsigned short*)alloc(MAT);
    unsigned short* WqT = (unsigned short*)alloc(WMAT);
    unsigned short* WkT = (unsigned short*)alloc(WMAT);
    unsigned short* WvT = (unsigned short*)alloc(WMAT);
    unsigned short* WoT = (unsigned short*)alloc(WMAT);
    unsigned short* qh  = (unsigned short*)alloc(MAT);
    unsigned short* kh  = (unsigned short*)alloc(MAT);
    unsigned short* vhT = (unsigned short*)alloc(MAT);
    unsigned short* ao  = (unsigned short*)alloc(MAT);
    uint32_t* pmask     = (uint32_t*)alloc((size_t)NB * S_LEN * 64 * 4);

    // K-split partials overlay the qb/kb/vb region (dead after proj_gemm):
    // pob: 4 * S * DM bf16 = 12.58 MB (fits in qb+kb), lsb: 4*NH*S fp32 = 0.39 MB (in vb)
    unsigned short* pob = (unsigned short*)ws;
    float* lsb = (float*)(ws + (size_t)4 * S_LEN * DM * 2);

    cvt_kernel<<<dim3(3072, 3), 256, 0, stream>>>(q, k, v, qb, kb, vb);
    wtrans_kernel<<<dim3(2304, 4), 256, 0, stream>>>(Wq, Wk, Wv, Wo, WqT, WkT, WvT, WoT);
    mask_pack<<<dim3(32768), 256, 0, stream>>>(mask, pmask);
    proj_gemm<<<dim3(32, 6, 3), 256, 0, stream>>>(qb, kb, vb, WqT, WkT, WvT, qh, kh, vhT);
    attn_kernel<<<dim3(16, 12, 4), 256, 0, stream>>>(qh, kh, vhT, pmask, pob, lsb);
    merge_kernel<<<dim3(3072), 256, 0, stream>>>(pob, lsb, ao);
    out_gemm<<<dim3(32, 6), 256, 0, stream>>>(ao, WoT, out);
}